// Round 2
// baseline (177.211 us; speedup 1.0000x reference)
//
#include <hip/hip_runtime.h>
#include <hip/hip_bf16.h>

typedef __attribute__((ext_vector_type(8))) __bf16 bf16x8;
typedef __attribute__((ext_vector_type(4))) float f32x4;

#define BATCH   1048576
#define DISTIL  128
#define CLASSES 64

// One wave computes a 16-row x 64-class output tile with 4x mfma_f32_16x16x32_bf16,
// computed TRANSPOSED: D = W^T (16 classes x 32k) * z^T (32k x 16 batch).
//   A fragment (16x32): lane l holds A[row=l&15][k=(l>>4)*8+j]  -> W[k][n*16 + (l&15)]
//   B fragment (32x16): lane l holds B[k=(l>>4)*8+j][col=l&15]  -> z[batch=l&15][k]
//   D fragment:         lane l, reg j -> D[class=(l>>4)*4+j][batch=l&15]   (m89-verified)
// => lane l holds out[rowbase + (l&15)][n*16 + (l>>4)*4 + j], j=0..3 contiguous
//    -> single dwordx4 store per n-group.
__global__ __launch_bounds__(256, 4) void linclass_kernel(
    const float* __restrict__ z, const float* __restrict__ W,
    const float* __restrict__ bias, float* __restrict__ out)
{
    const int lane = threadIdx.x & 63;
    const int wave = threadIdx.x >> 6;
    const int l15  = lane & 15;
    const int lhi  = lane >> 4;      // 0..3

    // ---- bias: lane l needs bias[n*16 + lhi*4 + j], j=0..3 -> vector load ----
    f32x4 bias4[4];
#pragma unroll
    for (int n = 0; n < 4; ++n)
        bias4[n] = *(const f32x4*)(bias + n * 16 + lhi * 4);

    // ---- W fragments (A operand), held in registers for the whole kernel ----
    // bw[n][kk][j] = W[kk*32 + lhi*8 + j][n*16 + l15]   (32 KB total; L2-hot)
    bf16x8 bw[4][4];
#pragma unroll
    for (int n = 0; n < 4; ++n) {
#pragma unroll
        for (int kk = 0; kk < 4; ++kk) {
            const int c     = n * 16 + l15;
            const int kbase = kk * 32 + lhi * 8;
#pragma unroll
            for (int j = 0; j < 8; ++j) {
                bw[n][kk][j] = (__bf16)W[(kbase + j) * CLASSES + c];
            }
        }
    }

    const long gwave  = (long)blockIdx.x * 4 + wave;
    const long nwaves = (long)gridDim.x * 4;
    const long ntiles = BATCH / 16;   // 65536, divides exactly

    for (long t = gwave; t < ntiles; t += nwaves) {
        const long rowbase = t * 16;

        f32x4 acc[4];
#pragma unroll
        for (int n = 0; n < 4; ++n) acc[n] = bias4[n];

        // z loads: lane l reads z[rowbase + l15][kk*32 + lhi*8 .. +8] (32 B, nt)
        const float* zrow = z + (rowbase + l15) * (long)DISTIL;
#pragma unroll
        for (int kk = 0; kk < 4; ++kk) {
            const float* p = zrow + kk * 32 + lhi * 8;
            f32x4 x0 = __builtin_nontemporal_load((const f32x4*)p);
            f32x4 x1 = __builtin_nontemporal_load((const f32x4*)p + 1);
            bf16x8 a;
#pragma unroll
            for (int j = 0; j < 4; ++j) {
                a[j]     = (__bf16)x0[j];
                a[4 + j] = (__bf16)x1[j];
            }
#pragma unroll
            for (int n = 0; n < 4; ++n)
                acc[n] = __builtin_amdgcn_mfma_f32_16x16x32_bf16(bw[n][kk], a, acc[n], 0, 0, 0);
        }

        // store: lane l writes out[rowbase + l15][n*16 + lhi*4 .. +4] as dwordx4 (nt)
        float* orow = out + (rowbase + l15) * (long)CLASSES + lhi * 4;
#pragma unroll
        for (int n = 0; n < 4; ++n) {
            __builtin_nontemporal_store(acc[n], (f32x4*)(orow + n * 16));
        }
    }
}

extern "C" void kernel_launch(void* const* d_in, const int* in_sizes, int n_in,
                              void* d_out, int out_size, void* d_ws, size_t ws_size,
                              hipStream_t stream) {
    const float* z    = (const float*)d_in[0];   // [1048576, 128]
    const float* W    = (const float*)d_in[1];   // [128, 64]
    const float* bias = (const float*)d_in[2];   // [64]
    float* out        = (float*)d_out;           // [1048576, 64]

    // 1024 blocks x 4 waves = 4096 waves = 16 waves/CU (exact static balance:
    // 65536 tiles / 4096 waves = 16 tiles per wave).
    dim3 grid(1024), block(256);
    linclass_kernel<<<grid, block, 0, stream>>>(z, W, bias, out);
}

// Round 3
// 148.630 us; speedup vs baseline: 1.1923x; 1.1923x over previous
//
#include <hip/hip_runtime.h>
#include <hip/hip_bf16.h>

typedef __attribute__((ext_vector_type(8))) __bf16 bf16x8;
typedef __attribute__((ext_vector_type(4))) float f32x4;

#define BATCH   1048576
#define DISTIL  128
#define CLASSES 64
#define NWAVES  4096          // 1024 blocks x 4 waves (launch must match)
#define NTILES  (BATCH / 16)  // 65536
#define TPW     16            // tiles per wave, exact

// D = W^T * z^T (transposed GEMM), 16x16x32 bf16 MFMA:
//   A frag: lane l holds W[kk*32+(l>>4)*8+j][n*16+(l&15)]
//   B frag: lane l holds z[batch=l&15][kk*32+(l>>4)*8+j]
//   D frag: lane l, reg j -> out[batch=l&15][n*16+(l>>4)*4+j]  (contiguous dwordx4)
// W fragments prepacked in LDS (16 frags x 64 lanes x 16B = 16 KB), read per tile
// via asm-volatile ds_read_b128 (keeps them OUT of persistent VGPRs). z is
// double-buffered in registers with next-tile prefetch to keep HBM reads in flight.

#define PREFETCH(buf, t) do {                                                  \
    const float* zr_ = z + ((t) * 16 + l15) * (long)DISTIL + lhi * 8;          \
    buf[0] = *(const f32x4*)(zr_);       buf[1] = *(const f32x4*)(zr_ + 4);    \
    buf[2] = *(const f32x4*)(zr_ + 32);  buf[3] = *(const f32x4*)(zr_ + 36);   \
    buf[4] = *(const f32x4*)(zr_ + 64);  buf[5] = *(const f32x4*)(zr_ + 68);   \
    buf[6] = *(const f32x4*)(zr_ + 96);  buf[7] = *(const f32x4*)(zr_ + 100);  \
} while (0)

#define KKSTEP(buf, kk) do {                                                   \
    f32x4 x0_ = buf[2*(kk)], x1_ = buf[2*(kk)+1];                              \
    bf16x8 a_;                                                                 \
    for (int j = 0; j < 4; ++j) { a_[j] = (__bf16)x0_[j]; a_[4+j] = (__bf16)x1_[j]; } \
    bf16x8 b0_, b1_, b2_, b3_;                                                 \
    asm volatile("ds_read_b128 %0, %1 offset:%2" : "=v"(b0_) : "v"(waddr), "n"((0*4+(kk))*1024)); \
    asm volatile("ds_read_b128 %0, %1 offset:%2" : "=v"(b1_) : "v"(waddr), "n"((1*4+(kk))*1024)); \
    asm volatile("ds_read_b128 %0, %1 offset:%2" : "=v"(b2_) : "v"(waddr), "n"((2*4+(kk))*1024)); \
    asm volatile("ds_read_b128 %0, %1 offset:%2" : "=v"(b3_) : "v"(waddr), "n"((3*4+(kk))*1024)); \
    asm volatile("s_waitcnt lgkmcnt(0)" ::: "memory");                         \
    __builtin_amdgcn_sched_barrier(0);                                         \
    acc0 = __builtin_amdgcn_mfma_f32_16x16x32_bf16(b0_, a_, acc0, 0, 0, 0);    \
    acc1 = __builtin_amdgcn_mfma_f32_16x16x32_bf16(b1_, a_, acc1, 0, 0, 0);    \
    acc2 = __builtin_amdgcn_mfma_f32_16x16x32_bf16(b2_, a_, acc2, 0, 0, 0);    \
    acc3 = __builtin_amdgcn_mfma_f32_16x16x32_bf16(b3_, a_, acc3, 0, 0, 0);    \
} while (0)

#define COMPUTE(buf, t) do {                                                   \
    f32x4 acc0, acc1, acc2, acc3;                                              \
    asm volatile("ds_read_b128 %0, %1 offset:0"   : "=v"(acc0) : "v"(baddr));  \
    asm volatile("ds_read_b128 %0, %1 offset:64"  : "=v"(acc1) : "v"(baddr));  \
    asm volatile("ds_read_b128 %0, %1 offset:128" : "=v"(acc2) : "v"(baddr));  \
    asm volatile("ds_read_b128 %0, %1 offset:192" : "=v"(acc3) : "v"(baddr));  \
    asm volatile("s_waitcnt lgkmcnt(0)" ::: "memory");                         \
    __builtin_amdgcn_sched_barrier(0);                                         \
    KKSTEP(buf, 0); KKSTEP(buf, 1); KKSTEP(buf, 2); KKSTEP(buf, 3);            \
    float* orow_ = out + ((t) * 16 + l15) * (long)CLASSES + lhi * 4;           \
    *(f32x4*)(orow_)      = acc0;                                              \
    *(f32x4*)(orow_ + 16) = acc1;                                              \
    *(f32x4*)(orow_ + 32) = acc2;                                              \
    *(f32x4*)(orow_ + 48) = acc3;                                              \
} while (0)

__global__ __launch_bounds__(256, 4) void linclass_kernel(
    const float* __restrict__ z, const float* __restrict__ W,
    const float* __restrict__ bias, float* __restrict__ out)
{
    const int lane = threadIdx.x & 63;
    const int w    = threadIdx.x >> 6;   // wave id 0..3
    const int l15  = lane & 15;
    const int lhi  = lane >> 4;          // 0..3

    // ---- prepack W fragments into LDS: frag f=(n*4+kk) at f*1024 + lane*16 ----
    __shared__ __align__(16) unsigned char wlds_s[16 * 64 * 16];
    __shared__ __align__(16) float blds_s[64];
    // wave w writes the 4 frags for n == w
    for (int kk = 0; kk < 4; ++kk) {
        bf16x8 fr;
        for (int j = 0; j < 8; ++j)
            fr[j] = (__bf16)W[(kk * 32 + lhi * 8 + j) * CLASSES + w * 16 + l15];
        *(bf16x8*)&wlds_s[((w * 4 + kk) * 64 + lane) * 16] = fr;
    }
    if (threadIdx.x < 64) blds_s[threadIdx.x] = bias[threadIdx.x];
    __syncthreads();

    const uint32_t waddr = (uint32_t)(uintptr_t)&wlds_s[0] + lane * 16;
    const uint32_t baddr = (uint32_t)(uintptr_t)&blds_s[0] + lhi * 16;

    const long gwave = (long)blockIdx.x * 4 + w;   // 0..4095

    // ---- 16 tiles per wave, register double-buffered prefetch ----
    f32x4 bufA[8], bufB[8];
    PREFETCH(bufA, gwave);
#pragma unroll
    for (int i = 0; i < TPW; i += 2) {
        const long ta = gwave + (long)i * NWAVES;
        const long tb = ta + NWAVES;                 // i+1 <= 15, always valid
        PREFETCH(bufB, tb);
        COMPUTE(bufA, ta);
        if (i + 2 < TPW) PREFETCH(bufA, tb + NWAVES);
        COMPUTE(bufB, tb);
    }
}

extern "C" void kernel_launch(void* const* d_in, const int* in_sizes, int n_in,
                              void* d_out, int out_size, void* d_ws, size_t ws_size,
                              hipStream_t stream) {
    const float* z    = (const float*)d_in[0];   // [1048576, 128]
    const float* W    = (const float*)d_in[1];   // [128, 64]
    const float* bias = (const float*)d_in[2];   // [64]
    float* out        = (float*)d_out;           // [1048576, 64]

    dim3 grid(1024), block(256);                 // 4096 waves == NWAVES
    linclass_kernel<<<grid, block, 0, stream>>>(z, W, bias, out);
}